// Round 21
// baseline (1208.132 us; speedup 1.0000x reference)
//
#include <hip/hip_runtime.h>
#include <cstdint>

typedef unsigned short u16;
typedef unsigned int u32;
typedef __attribute__((ext_vector_type(4))) int int4v;
typedef __attribute__((ext_vector_type(8))) short short8;
typedef __attribute__((ext_vector_type(4))) float f32x4;

// d_out layout (floats): [xloss(1), nonpadded(1), pred(130048), Q(1), idx(1024)]
#define XLOSS_OFF 0
#define NPAD_OFF  1
#define PRED_OFF  2
#define Q_OFF     130050
#define IDX_OFF   130051

__device__ __forceinline__ u16 f2b(float f){
  union { float f; unsigned int i; } c; c.f = f;
  unsigned int i = c.i;
  unsigned int r = (i + 0x7FFFu + ((i >> 16) & 1u)) >> 16;
  return (u16)r;
}

#define LOG2E 1.442695040889634f
__device__ __forceinline__ float fast_sigmoid(float x){
  return __builtin_amdgcn_rcpf(1.f + __builtin_amdgcn_exp2f(-LOG2E*x));
}
__device__ __forceinline__ float fast_tanh(float x){
  return 1.f - 2.f*__builtin_amdgcn_rcpf(1.f + __builtin_amdgcn_exp2f((2.f*LOG2E)*x));
}

// ---------------- fused prep: Wout bf16 + i8 quant + G tables ----------------
__global__ __launch_bounds__(256) void k_prep(
    const float* __restrict__ Wo, u16* __restrict__ oWo,
    const float* __restrict__ Wf, const float* __restrict__ Wb, const float* __restrict__ Wd,
    signed char* __restrict__ qf, signed char* __restrict__ qb, signed char* __restrict__ qd,
    float* __restrict__ invf, float* __restrict__ invb, float* __restrict__ invd,
    const float* __restrict__ emb_e, const float* __restrict__ emb_d,
    const float* __restrict__ Wih_f, const float* __restrict__ bih_f, const float* __restrict__ bhh_f,
    const float* __restrict__ Wih_b, const float* __restrict__ bih_b, const float* __restrict__ bhh_b,
    const float* __restrict__ Wih_d,
    float* __restrict__ Gf, float* __restrict__ Gb, float* __restrict__ Gd,
    float* __restrict__ dout){
  const int blk = blockIdx.x;
  const int tid = threadIdx.x;
  if (blk < 64){
    int idx = blk*256 + tid;
    if (idx == 0){ dout[XLOSS_OFF]=0.f; dout[NPAD_OFF]=0.f; dout[Q_OFF]=0.f; }
    int row = idx >> 8, k = idx & 255;
    oWo[idx] = (row < 51) ? f2b(Wo[row*256 + k]) : (u16)0;
  } else if (blk < 640){
    const int row = (blk-64)*4 + (tid >> 6);   // 0..2303, one wave per row
    const int lane = tid & 63;
    const int mat = row / 768, r = row - mat*768;
    const float* W = (mat==0 ? Wf : (mat==1 ? Wb : Wd)) + (size_t)r*256;
    signed char* q = (mat==0 ? qf : (mat==1 ? qb : qd)) + (size_t)r*256;
    float* inv     = (mat==0 ? invf : (mat==1 ? invb : invd));
    float4 v = *(const float4*)(W + lane*4);
    float m = fmaxf(fmaxf(fabsf(v.x),fabsf(v.y)), fmaxf(fabsf(v.z),fabsf(v.w)));
    #pragma unroll
    for (int off=32; off>0; off>>=1) m = fmaxf(m, __shfl_xor(m, off));
    m = fmaxf(m, 1e-20f);
    const float s = 127.f / m;
    int a0 = __float2int_rn(v.x*s), a1 = __float2int_rn(v.y*s);
    int a2 = __float2int_rn(v.z*s), a3 = __float2int_rn(v.w*s);
    u32 packed = (a0&255) | ((a1&255)<<8) | ((a2&255)<<16) | ((a3&255)<<24);
    *(u32*)(q + lane*4) = packed;
    if (lane == 0) inv[r] = m * (1.f/127.f);
  } else {
    int idx = (blk-640)*256 + tid;            // 0..117503 = 3*51*768
    int tab = idx / 39168;
    int rem = idx - tab*39168;
    int v = rem / 768;
    int n = rem - v*768;
    float acc = 0.f;
    if (tab == 0){
      const float* e = emb_e + v*64; const float* w = Wih_f + n*64;
      for (int k=0;k<64;k++) acc += e[k]*w[k];
      acc += bih_f[n] + (n < 512 ? bhh_f[n] : 0.f);
      Gf[rem] = acc;
    } else if (tab == 1){
      const float* e = emb_e + v*64; const float* w = Wih_b + n*64;
      for (int k=0;k<64;k++) acc += e[k]*w[k];
      acc += bih_b[n] + (n < 512 ? bhh_b[n] : 0.f);
      Gb[rem] = acc;
    } else {
      const float* e = emb_d + v*64; const float* w = Wih_d + n*96 + 32;
      for (int k=0;k<64;k++) acc += e[k]*w[k];
      Gd[rem] = acc;
    }
  }
}

// ---------------- GRU scan: 2 independent blocks/CU (4 waves/SIMD) ----------------
// 512 threads, ROWS rows/block (enc 4 -> 512 blocks, dec 2 -> 512 blocks) = 2
// blocks per CU. Blocks do NOT share barriers: while one block is in its gate/
// barrier phase the other's MFMA waves issue -> phase overlap across blocks.
// waves_per_eu(4,4) permits 4 waves/SIMD (2x512thr, VGPR<=128). Wave owns 32
// h-cols x 3 gates, 96 resident weight VGPRs. Raw i32 accs -> gh LDS; gate:
// TPR=512/ROWS thr/row, CPL cols/lane (enc 2, dec 1); truncated-bf16 ys.
template<int MODE, int ROWS>
__global__ __launch_bounds__(512)
__attribute__((amdgpu_waves_per_eu(4, 4)))
void k_gru(
    const signed char* __restrict__ W0, const signed char* __restrict__ W1,
    const float* __restrict__ I0, const float* __restrict__ I1,
    const float* __restrict__ G0, const float* __restrict__ G1,
    const float* __restrict__ bhh0, const float* __restrict__ bhh1,
    const int* __restrict__ x,
    const float* __restrict__ zc, const float* __restrict__ h0g,
    float* __restrict__ out_h, u16* __restrict__ ys){
  constexpr int TPR = 512 / ROWS;
  constexpr int CPL = 256 / TPR;             // enc 2, dec 1
  constexpr int RD  = (ROWS < 4) ? ROWS : 4; // valid rows per acc dump

  __shared__ signed char hbf[2*4096];
  __shared__ int xsh[ROWS*128];
  __shared__ int gh[ROWS*772];
  __shared__ float zcs[(MODE==1) ? ROWS*768 : 4];

  const int tid = threadIdx.x;
  const int lane = tid & 63;
  const int wave = tid >> 6;
  const int l15 = lane & 15, lhi = lane >> 4;

  bool fwd = true; int gb;
  const signed char* W; const float* G; const float* bhh; const float* invS;
  if (MODE == 0){
    const int nblk = 1024 / ROWS;
    int bi = blockIdx.x;
    fwd = bi < nblk; gb = fwd ? bi : bi - nblk;
    W = fwd ? W0 : W1; G = fwd ? G0 : G1; bhh = fwd ? bhh0 : bhh1;
    invS = fwd ? I0 : I1;
  } else {
    gb = blockIdx.x; W = W0; G = G0; bhh = bhh0; invS = I0;
  }
  const int b0 = gb * ROWS;
  const int nT = (MODE == 0) ? 128 : 127;
  const float HS    = (MODE == 0) ? 127.f : 63.f;
  const float invHS = (MODE == 0) ? (1.f/127.f) : (1.f/63.f);

  // ---- persistent weights: 24 x int4v = 96 VGPRs, pinned ----
  int4v wq[6][4];
  #pragma unroll
  for (int g=0; g<3; g++){
    #pragma unroll
    for (int hh=0; hh<2; hh++){
      const signed char* p = W + (size_t)(g*256 + wave*32 + hh*16 + l15)*256 + lhi*16;
      #pragma unroll
      for (int kt=0; kt<4; kt++)
        wq[g*2+hh][kt] = *(const int4v*)(p + kt*64);
    }
  }
  #pragma unroll
  for (int kt=0; kt<4; kt++){
    asm volatile("" : "+v"(wq[0][kt]));
    asm volatile("" : "+v"(wq[1][kt]));
    asm volatile("" : "+v"(wq[2][kt]));
    asm volatile("" : "+v"(wq[3][kt]));
    asm volatile("" : "+v"(wq[4][kt]));
    asm volatile("" : "+v"(wq[5][kt]));
  }

  // ---- gate identity + scales ----
  const int gm = tid / TPR;
  const int ci = (tid % TPR) * CPL;
  float isr[CPL], isz[CPL], isn[CPL], bnv[CPL];
  #pragma unroll
  for (int i=0;i<CPL;i++){
    isr[i] = invS[ci+i]       * invHS;
    isz[i] = invS[256 + ci+i] * invHS;
    isn[i] = invS[512 + ci+i] * invHS;
    bnv[i] = bhh[512 + ci+i];
  }

  for (int i = tid; i < ROWS*128; i += 512) xsh[i] = x[b0*128 + i];
  for (int i = tid*4; i < 8192; i += 2048) *(int*)&hbf[i] = 0;
  if (MODE == 1){
    const f32x4* src = (const f32x4*)(zc + (size_t)b0*768);
    f32x4* dst = (f32x4*)zcs;
    for (int i = tid; i < ROWS*192; i += 512) dst[i] = src[i];
  }
  __syncthreads();

  float hreg[CPL];
  #pragma unroll
  for (int i=0;i<CPL;i++) hreg[i] = 0.f;
  if (MODE == 1){
    #pragma unroll
    for (int i=0;i<CPL;i++){
      float hv = h0g[(size_t)(b0+gm)*256 + ci+i];
      hreg[i] = hv;
      int q = __float2int_rn(fminf(fmaxf(hv*HS, -127.f), 127.f));
      hbf[gm*256 + ((ci+i) ^ (gm<<4))] = (signed char)q;
    }
  }
  __syncthreads();

  int aoff[4];
  #pragma unroll
  for (int kt=0; kt<4; kt++)
    aoff[kt] = l15*256 + ((kt*64 + lhi*16) ^ (l15<<4));

  int cur = 0;
  for (int t=0; t<nT; ++t){
    const int te = (MODE==0 && !fwd) ? (127 - t) : t;
    const int tok = xsh[(gm<<7) + te];
    const float* Gp = G + (size_t)tok*768 + ci;
    float gvr[CPL], gvz[CPL], gvn[CPL];
    #pragma unroll
    for (int i=0;i<CPL;i++){
      gvr[i] = Gp[i]; gvz[i] = Gp[256+i]; gvn[i] = Gp[512+i];
    }

    const signed char* hb = hbf + (cur<<12);
    int4v af[4];
    #pragma unroll
    for (int kt=0; kt<4; kt++) af[kt] = *(const int4v*)(hb + aoff[kt]);

    int4v acc[6];
    #pragma unroll
    for (int j=0;j<6;j++) acc[j] = (int4v){0,0,0,0};
    #pragma unroll
    for (int kt=0; kt<4; kt++)
      #pragma unroll
      for (int j=0;j<6;j++)
        acc[j] = __builtin_amdgcn_mfma_i32_16x16x64_i8(af[kt], wq[j][kt], acc[j], 0,0,0);

    if (4*lhi < ROWS){
      #pragma unroll
      for (int j=0;j<6;j++){
        const int g = j >> 1;
        const int col = wave*32 + (j&1)*16 + l15;
        #pragma unroll
        for (int r=0;r<RD;r++)
          gh[(4*lhi+r)*772 + g*256 + col] = acc[j][r];
      }
    }
    __syncthreads();

    // ---- gate phase ----
    int hiR[CPL], hiZ[CPL], hiN[CPL];
    #pragma unroll
    for (int i=0;i<CPL;i++){
      hiR[i] = gh[gm*772 + ci+i];
      hiZ[i] = gh[gm*772 + 256 + ci+i];
      hiN[i] = gh[gm*772 + 512 + ci+i];
    }
    if (MODE == 1){
      #pragma unroll
      for (int i=0;i<CPL;i++){
        gvr[i] += zcs[gm*768 + ci+i];
        gvz[i] += zcs[gm*768 + 256 + ci+i];
        gvn[i] += zcs[gm*768 + 512 + ci+i];
      }
    }
    #pragma unroll
    for (int i=0;i<CPL;i++){
      float rg = fast_sigmoid((float)hiR[i]*isr[i] + gvr[i]);
      float zg = fast_sigmoid((float)hiZ[i]*isz[i] + gvz[i]);
      float nn = fast_tanh(gvn[i] + rg*((float)hiN[i]*isn[i] + bnv[i]));
      hreg[i] = nn + zg*(hreg[i] - nn);
    }
    if constexpr (MODE == 0){
      // |h| <= 1 (tanh + convex combo from h0=0): clamp-free pack (CPL==2)
      int q0 = __float2int_rn(hreg[0]*127.f);
      int q1 = __float2int_rn(hreg[1]*127.f);
      *(u16*)&hbf[((cur^1)<<12) + gm*256 + (ci ^ (gm<<4))] =
          (u16)((q0 & 255) | ((q1 & 255) << 8));
    } else {
      // decoder CPL==1
      int q0 = __float2int_rn(fminf(fmaxf(hreg[0]*HS, -127.f), 127.f));
      hbf[((cur^1)<<12) + gm*256 + (ci ^ (gm<<4))] = (signed char)q0;
      u32 fa = __builtin_bit_cast(u32, hreg[0]);
      ys[((size_t)(b0+gm)*127 + t)*256 + ci] = (u16)(fa >> 16);
    }
    __syncthreads();
    cur ^= 1;
  }

  if (MODE == 0){
    #pragma unroll
    for (int i=0;i<CPL;i++)
      out_h[(size_t)(b0+gm)*512 + (fwd ? 0 : 256) + ci+i] = hreg[i];
  }
}

// ---------------- VQ: z, argmin codebook, Q, idx, decoder h0, zc ----------------
__global__ __launch_bounds__(64) void k_vq(
    const float* __restrict__ outH, const float* __restrict__ Wdown, const float* __restrict__ bdown,
    const float* __restrict__ cb, const float* __restrict__ Wup, const float* __restrict__ bup,
    const float* __restrict__ Wihd, const float* __restrict__ bihd, const float* __restrict__ bhhd,
    float* __restrict__ hidden, float* __restrict__ zc, float* __restrict__ dout){
  const int b = blockIdx.x;
  const int lane = threadIdx.x;
  __shared__ float oh[512];
  __shared__ float zsh[32];
  __shared__ float qsh[32];
  {
    const float* src = outH + (size_t)b*512 + lane*8;
    *(float4*)&oh[lane*8]   = *(const float4*)src;
    *(float4*)&oh[lane*8+4] = *(const float4*)(src+4);
  }
  __syncthreads();
  if (lane < 32){
    float acc = bdown[lane];
    const float* wr = Wdown + lane*512;
    for (int k=0;k<512;k++) acc += wr[k]*oh[k];
    zsh[lane] = acc;
  }
  __syncthreads();
  float bd = 3.4e38f; int bi = 0;
  for (int c8=0;c8<8;c8++){
    const int c = lane*8 + c8;
    const float* cr = cb + c*32;
    float d = 0.f;
    #pragma unroll
    for (int k=0;k<32;k++){ float df = zsh[k]-cr[k]; d += df*df; }
    if (d < bd){ bd = d; bi = c; }
  }
  #pragma unroll
  for (int offm=32; offm>0; offm>>=1){
    float od = __shfl_xor(bd, offm);
    int   oi = __shfl_xor(bi, offm);
    if (od < bd || (od == bd && oi < bi)){ bd = od; bi = oi; }
  }
  if (lane == 0){
    atomicAdd(&dout[Q_OFF], bd * (0.2f/32.f));
    dout[IDX_OFF + b] = (float)bi;
  }
  if (lane < 32) qsh[lane] = cb[(size_t)bi*32 + lane];
  __syncthreads();
  #pragma unroll
  for (int i=0;i<4;i++){
    const int o = lane*4 + i;
    float acc = bup[o];
    const float* wr = Wup + o*32;
    #pragma unroll
    for (int k=0;k<32;k++) acc += wr[k]*qsh[k];
    hidden[(size_t)b*256 + o] = acc;
  }
  #pragma unroll
  for (int i=0;i<12;i++){
    const int o = lane*12 + i;
    float acc = bihd[o] + (o < 512 ? bhhd[o] : 0.f);
    const float* wr = Wihd + (size_t)o*96;
    #pragma unroll
    for (int k=0;k<32;k++) acc += wr[k]*qsh[k];
    zc[(size_t)b*768 + o] = acc;
  }
}

// ---------------- output: logits, log-softmax, nll, argmax ----------------
__global__ __launch_bounds__(256) void k_out(
    const u16* __restrict__ ys, const u16* __restrict__ Wo,
    const float* __restrict__ bout, const int* __restrict__ x,
    float* __restrict__ dout){
  const int tid = threadIdx.x;
  const int w = tid >> 6, lane = tid & 63;
  const int l15 = lane & 15, lhi = lane >> 4;
  __shared__ float lg[4][32][66];
  const int rows0 = blockIdx.x*128 + w*32;
  const f32x4 fz = {0.f,0.f,0.f,0.f};
  #pragma unroll
  for (int mt=0; mt<2; mt++){
    const int rb = rows0 + mt*16;
    f32x4 acc[4];
    #pragma unroll
    for (int nt=0;nt<4;nt++) acc[nt] = fz;
    #pragma unroll
    for (int kt=0; kt<8; kt++){
      short8 a = *(const short8*)&ys[(size_t)(rb + l15)*256 + kt*32 + lhi*8];
      #pragma unroll
      for (int nt=0; nt<4; nt++){
        short8 bb = *(const short8*)&Wo[(size_t)(nt*16 + l15)*256 + kt*32 + lhi*8];
        acc[nt] = __builtin_amdgcn_mfma_f32_16x16x32_bf16(a, bb, acc[nt], 0, 0, 0);
      }
    }
    #pragma unroll
    for (int nt=0;nt<4;nt++){
      const int col = nt*16 + l15;
      const float bo = (col < 51) ? bout[col] : 0.f;
      #pragma unroll
      for (int r=0;r<4;r++){
        float v = (col < 51) ? (acc[nt][r] + bo) : -1e30f;
        lg[w][mt*16 + lhi*4 + r][col] = v;
      }
    }
  }
  __syncthreads();
  float xl = 0.f, ct = 0.f;
  if (lane < 32){
    const int grow = rows0 + lane;
    const float* Lr = &lg[w][lane][0];
    float m = Lr[0]; int am = 0;
    for (int i=1;i<51;i++){ float v = Lr[i]; if (v > m){ m = v; am = i; } }
    float s = 0.f;
    for (int i=0;i<51;i++) s += __expf(Lr[i] - m);
    const int bb = grow / 127;
    const int tt = grow - bb*127;
    const int tgt = x[bb*128 + tt + 1];
    const float nll = (m + __logf(s)) - Lr[tgt];
    const float mk = (tgt != 0) ? 1.f : 0.f;
    dout[PRED_OFF + grow] = (float)am;
    xl = nll * mk; ct = mk;
  }
  #pragma unroll
  for (int off=32; off>0; off>>=1){
    xl += __shfl_xor(xl, off);
    ct += __shfl_xor(ct, off);
  }
  if (lane == 0){
    atomicAdd(&dout[XLOSS_OFF], xl);
    atomicAdd(&dout[NPAD_OFF], ct);
  }
}

extern "C" void kernel_launch(void* const* d_in, const int* in_sizes, int n_in,
                              void* d_out, int out_size, void* d_ws, size_t ws_size,
                              hipStream_t stream){
  (void)in_sizes; (void)n_in; (void)out_size; (void)ws_size;
  const int*   x      = (const int*)  d_in[0];
  const float* emb_e  = (const float*)d_in[1];
  const float* emb_d  = (const float*)d_in[2];
  const float* Wih_f  = (const float*)d_in[3];
  const float* Whh_f  = (const float*)d_in[4];
  const float* bih_f  = (const float*)d_in[5];
  const float* bhh_f  = (const float*)d_in[6];
  const float* Wih_b  = (const float*)d_in[7];
  const float* Whh_b  = (const float*)d_in[8];
  const float* bih_b  = (const float*)d_in[9];
  const float* bhh_b  = (const float*)d_in[10];
  const float* Wdown  = (const float*)d_in[11];
  const float* bdown  = (const float*)d_in[12];
  const float* cbook  = (const float*)d_in[13];
  const float* Wup    = (const float*)d_in[14];
  const float* bup    = (const float*)d_in[15];
  const float* Wih_d  = (const float*)d_in[16];
  const float* Whh_d  = (const float*)d_in[17];
  const float* bih_d  = (const float*)d_in[18];
  const float* bhh_d  = (const float*)d_in[19];
  const float* Wout   = (const float*)d_in[20];
  const float* bout   = (const float*)d_in[21];
  float* dout = (float*)d_out;

  char* ws = (char*)d_ws;
  size_t off = 0;
  auto nxt = [&](size_t bytes)->char*{
    char* r = ws + off;
    off += (bytes + 255) & ~(size_t)255;
    return r;
  };
  signed char* Wq_f = (signed char*)nxt((size_t)196608);
  signed char* Wq_b = (signed char*)nxt((size_t)196608);
  signed char* Wq_d = (signed char*)nxt((size_t)196608);
  float* invF = (float*)nxt((size_t)768*4);
  float* invB = (float*)nxt((size_t)768*4);
  float* invD = (float*)nxt((size_t)768*4);
  float* Gf    = (float*)nxt((size_t)39168*4);
  float* Gb    = (float*)nxt((size_t)39168*4);
  float* Gd    = (float*)nxt((size_t)39168*4);
  u16*   Wo_bf = (u16*) nxt((size_t)16384*2);
  float* outH  = (float*)nxt((size_t)524288*4);
  float* hid   = (float*)nxt((size_t)262144*4);
  float* zcw   = (float*)nxt((size_t)786432*4);
  u16*   ysb   = (u16*)  nxt((size_t)33292288*2);

  hipLaunchKernelGGL(k_prep, dim3(1099), dim3(256), 0, stream,
                     Wout, Wo_bf,
                     Whh_f, Whh_b, Whh_d, Wq_f, Wq_b, Wq_d, invF, invB, invD,
                     emb_e, emb_d, Wih_f, bih_f, bhh_f, Wih_b, bih_b, bhh_b, Wih_d,
                     Gf, Gb, Gd, dout);
  hipLaunchKernelGGL((k_gru<0,4>), dim3(512), dim3(512), 0, stream,
                     Wq_f, Wq_b, invF, invB, Gf, Gb, bhh_f, bhh_b, x,
                     (const float*)nullptr, (const float*)nullptr, outH, (u16*)nullptr);
  hipLaunchKernelGGL(k_vq, dim3(1024), dim3(64), 0, stream,
                     outH, Wdown, bdown, cbook, Wup, bup, Wih_d, bih_d, bhh_d,
                     hid, zcw, dout);
  hipLaunchKernelGGL((k_gru<1,2>), dim3(512), dim3(512), 0, stream,
                     Wq_d, (const signed char*)nullptr, invD, (const float*)nullptr,
                     Gd, (const float*)nullptr, bhh_d, (const float*)nullptr, x,
                     zcw, hid, (float*)nullptr, ysb);
  hipLaunchKernelGGL(k_out, dim3(1016), dim3(256), 0, stream,
                     ysb, Wo_bf, bout, x, dout);
}

// Round 22
// 480.727 us; speedup vs baseline: 2.5131x; 2.5131x over previous
//
#include <hip/hip_runtime.h>
#include <cstdint>

typedef unsigned short u16;
typedef unsigned int u32;
typedef __attribute__((ext_vector_type(4))) int int4v;
typedef __attribute__((ext_vector_type(8))) short short8;
typedef __attribute__((ext_vector_type(4))) float f32x4;

// d_out layout (floats): [xloss(1), nonpadded(1), pred(130048), Q(1), idx(1024)]
#define XLOSS_OFF 0
#define NPAD_OFF  1
#define PRED_OFF  2
#define Q_OFF     130050
#define IDX_OFF   130051

__device__ __forceinline__ u16 f2b(float f){
  union { float f; unsigned int i; } c; c.f = f;
  unsigned int i = c.i;
  unsigned int r = (i + 0x7FFFu + ((i >> 16) & 1u)) >> 16;
  return (u16)r;
}

#define LOG2E 1.442695040889634f
__device__ __forceinline__ float fast_sigmoid(float x){
  return __builtin_amdgcn_rcpf(1.f + __builtin_amdgcn_exp2f(-LOG2E*x));
}
__device__ __forceinline__ float fast_tanh(float x){
  return 1.f - 2.f*__builtin_amdgcn_rcpf(1.f + __builtin_amdgcn_exp2f((2.f*LOG2E)*x));
}

// ---------------- fused prep: Wout bf16 + i8 quant + G tables ----------------
// blocks [0,64): Wout copy + zero scalars; [64,640): per-row i8 quant (4 rows/blk,
// one wave per row); [640,1099): G tables.
__global__ __launch_bounds__(256) void k_prep(
    const float* __restrict__ Wo, u16* __restrict__ oWo,
    const float* __restrict__ Wf, const float* __restrict__ Wb, const float* __restrict__ Wd,
    signed char* __restrict__ qf, signed char* __restrict__ qb, signed char* __restrict__ qd,
    float* __restrict__ invf, float* __restrict__ invb, float* __restrict__ invd,
    const float* __restrict__ emb_e, const float* __restrict__ emb_d,
    const float* __restrict__ Wih_f, const float* __restrict__ bih_f, const float* __restrict__ bhh_f,
    const float* __restrict__ Wih_b, const float* __restrict__ bih_b, const float* __restrict__ bhh_b,
    const float* __restrict__ Wih_d,
    float* __restrict__ Gf, float* __restrict__ Gb, float* __restrict__ Gd,
    float* __restrict__ dout){
  const int blk = blockIdx.x;
  const int tid = threadIdx.x;
  if (blk < 64){
    int idx = blk*256 + tid;
    if (idx == 0){ dout[XLOSS_OFF]=0.f; dout[NPAD_OFF]=0.f; dout[Q_OFF]=0.f; }
    int row = idx >> 8, k = idx & 255;
    oWo[idx] = (row < 51) ? f2b(Wo[row*256 + k]) : (u16)0;
  } else if (blk < 640){
    const int row = (blk-64)*4 + (tid >> 6);   // 0..2303, one wave per row
    const int lane = tid & 63;
    const int mat = row / 768, r = row - mat*768;
    const float* W = (mat==0 ? Wf : (mat==1 ? Wb : Wd)) + (size_t)r*256;
    signed char* q = (mat==0 ? qf : (mat==1 ? qb : qd)) + (size_t)r*256;
    float* inv     = (mat==0 ? invf : (mat==1 ? invb : invd));
    float4 v = *(const float4*)(W + lane*4);
    float m = fmaxf(fmaxf(fabsf(v.x),fabsf(v.y)), fmaxf(fabsf(v.z),fabsf(v.w)));
    #pragma unroll
    for (int off=32; off>0; off>>=1) m = fmaxf(m, __shfl_xor(m, off));
    m = fmaxf(m, 1e-20f);
    const float s = 127.f / m;
    int a0 = __float2int_rn(v.x*s), a1 = __float2int_rn(v.y*s);
    int a2 = __float2int_rn(v.z*s), a3 = __float2int_rn(v.w*s);
    u32 packed = (a0&255) | ((a1&255)<<8) | ((a2&255)<<16) | ((a3&255)<<24);
    *(u32*)(q + lane*4) = packed;
    if (lane == 0) inv[r] = m * (1.f/127.f);
  } else {
    int idx = (blk-640)*256 + tid;            // 0..117503 = 3*51*768
    int tab = idx / 39168;
    int rem = idx - tab*39168;
    int v = rem / 768;
    int n = rem - v*768;
    float acc = 0.f;
    if (tab == 0){
      const float* e = emb_e + v*64; const float* w = Wih_f + n*64;
      for (int k=0;k<64;k++) acc += e[k]*w[k];
      acc += bih_f[n] + (n < 512 ? bhh_f[n] : 0.f);
      Gf[rem] = acc;
    } else if (tab == 1){
      const float* e = emb_e + v*64; const float* w = Wih_b + n*64;
      for (int k=0;k<64;k++) acc += e[k]*w[k];
      acc += bih_b[n] + (n < 512 ? bhh_b[n] : 0.f);
      Gb[rem] = acc;
    } else {
      const float* e = emb_d + v*64; const float* w = Wih_d + n*96 + 32;
      for (int k=0;k<64;k++) acc += e[k]*w[k];
      Gd[rem] = acc;
    }
  }
}

// ---------------- GRU scan: best-known structure (R20) ----------------
// 512 threads (8 waves, waves_per_eu(2,2) -> 96 resident weight VGPRs, zero
// spills), ROWS rows/block (enc 8, dec 4; both grids 256 blocks = all CUs).
// Wave owns 32 h-cols x 3 gates via mfma_i32_16x16x64_i8 (i8 per-row-quantized
// weights; exact i32 accum, dequant by row-scale*h-scale). Raw i32 accs -> gh
// LDS; gate phase: TPR=512/ROWS thr/row, CPL cols/lane, all memory vectorized,
// G loads at loop top (latency hides under MFMA phase). Encoder h-store
// clamp-free v_perm pack (|h|<=1 provable); ys truncated-bf16 via v_perm.
template<int MODE, int ROWS>
__global__ __launch_bounds__(512)
__attribute__((amdgpu_waves_per_eu(2, 2)))
void k_gru(
    const signed char* __restrict__ W0, const signed char* __restrict__ W1,
    const float* __restrict__ I0, const float* __restrict__ I1,
    const float* __restrict__ G0, const float* __restrict__ G1,
    const float* __restrict__ bhh0, const float* __restrict__ bhh1,
    const int* __restrict__ x,
    const float* __restrict__ zc, const float* __restrict__ h0g,
    float* __restrict__ out_h, u16* __restrict__ ys){
  constexpr int TPR = 512 / ROWS;
  constexpr int CPL = 256 / TPR;             // enc 4, dec 2

  __shared__ signed char hbf[2*4096];
  __shared__ int xsh[ROWS*128];
  __shared__ int gh[ROWS*772];
  __shared__ float zcs[(MODE==1) ? ROWS*768 : 4];

  const int tid = threadIdx.x;
  const int lane = tid & 63;
  const int wave = tid >> 6;
  const int l15 = lane & 15, lhi = lane >> 4;

  bool fwd = true; int gb;
  const signed char* W; const float* G; const float* bhh; const float* invS;
  if (MODE == 0){
    const int nblk = 1024 / ROWS;
    int bi = blockIdx.x;
    fwd = bi < nblk; gb = fwd ? bi : bi - nblk;
    W = fwd ? W0 : W1; G = fwd ? G0 : G1; bhh = fwd ? bhh0 : bhh1;
    invS = fwd ? I0 : I1;
  } else {
    gb = blockIdx.x; W = W0; G = G0; bhh = bhh0; invS = I0;
  }
  const int b0 = gb * ROWS;
  const int nT = (MODE == 0) ? 128 : 127;
  const float HS    = (MODE == 0) ? 127.f : 63.f;
  const float invHS = (MODE == 0) ? (1.f/127.f) : (1.f/63.f);

  // ---- persistent weights: 24 x int4v = 96 VGPRs, pinned ----
  int4v wq[6][4];
  #pragma unroll
  for (int g=0; g<3; g++){
    #pragma unroll
    for (int hh=0; hh<2; hh++){
      const signed char* p = W + (size_t)(g*256 + wave*32 + hh*16 + l15)*256 + lhi*16;
      #pragma unroll
      for (int kt=0; kt<4; kt++)
        wq[g*2+hh][kt] = *(const int4v*)(p + kt*64);
    }
  }
  #pragma unroll
  for (int kt=0; kt<4; kt++){
    asm volatile("" : "+v"(wq[0][kt]));
    asm volatile("" : "+v"(wq[1][kt]));
    asm volatile("" : "+v"(wq[2][kt]));
    asm volatile("" : "+v"(wq[3][kt]));
    asm volatile("" : "+v"(wq[4][kt]));
    asm volatile("" : "+v"(wq[5][kt]));
  }

  // ---- gate identity + scales ----
  const int gm = tid / TPR;
  const int ci = (tid % TPR) * CPL;
  float isr[CPL], isz[CPL], isn[CPL], bnv[CPL];
  #pragma unroll
  for (int i=0;i<CPL;i++){
    isr[i] = invS[ci+i]       * invHS;
    isz[i] = invS[256 + ci+i] * invHS;
    isn[i] = invS[512 + ci+i] * invHS;
    bnv[i] = bhh[512 + ci+i];
  }

  for (int i = tid; i < ROWS*128; i += 512) xsh[i] = x[b0*128 + i];
  for (int i = tid*4; i < 8192; i += 2048) *(int*)&hbf[i] = 0;
  if (MODE == 1){
    const f32x4* src = (const f32x4*)(zc + (size_t)b0*768);
    f32x4* dst = (f32x4*)zcs;
    for (int i = tid; i < ROWS*192; i += 512) dst[i] = src[i];
  }
  __syncthreads();

  float hreg[CPL];
  #pragma unroll
  for (int i=0;i<CPL;i++) hreg[i] = 0.f;
  if (MODE == 1){
    #pragma unroll
    for (int i=0;i<CPL;i++){
      float hv = h0g[(size_t)(b0+gm)*256 + ci+i];
      hreg[i] = hv;
      int q = __float2int_rn(fminf(fmaxf(hv*HS, -127.f), 127.f));
      hbf[gm*256 + ((ci+i) ^ (gm<<4))] = (signed char)q;
    }
  }
  __syncthreads();

  int aoff[4];
  #pragma unroll
  for (int kt=0; kt<4; kt++)
    aoff[kt] = l15*256 + ((kt*64 + lhi*16) ^ (l15<<4));

  int cur = 0;
  for (int t=0; t<nT; ++t){
    const int te = (MODE==0 && !fwd) ? (127 - t) : t;
    const int tok = xsh[(gm<<7) + te];
    const float* Gp = G + (size_t)tok*768 + ci;
    float gvr[CPL], gvz[CPL], gvn[CPL];
    #pragma unroll
    for (int i=0;i<CPL;i++){
      gvr[i] = Gp[i]; gvz[i] = Gp[256+i]; gvn[i] = Gp[512+i];
    }

    const signed char* hb = hbf + (cur<<12);
    int4v af[4];
    #pragma unroll
    for (int kt=0; kt<4; kt++) af[kt] = *(const int4v*)(hb + aoff[kt]);

    int4v acc[6];
    #pragma unroll
    for (int j=0;j<6;j++) acc[j] = (int4v){0,0,0,0};
    #pragma unroll
    for (int kt=0; kt<4; kt++)
      #pragma unroll
      for (int j=0;j<6;j++)
        acc[j] = __builtin_amdgcn_mfma_i32_16x16x64_i8(af[kt], wq[j][kt], acc[j], 0,0,0);

    if (4*lhi < ROWS){
      #pragma unroll
      for (int j=0;j<6;j++){
        const int g = j >> 1;
        const int col = wave*32 + (j&1)*16 + l15;
        #pragma unroll
        for (int r=0;r<4;r++)
          gh[(4*lhi+r)*772 + g*256 + col] = acc[j][r];
      }
    }
    __syncthreads();

    // ---- gate phase ----
    int hiR[CPL], hiZ[CPL], hiN[CPL];
    #pragma unroll
    for (int i=0;i<CPL;i++){
      hiR[i] = gh[gm*772 + ci+i];
      hiZ[i] = gh[gm*772 + 256 + ci+i];
      hiN[i] = gh[gm*772 + 512 + ci+i];
    }
    if (MODE == 1){
      #pragma unroll
      for (int i=0;i<CPL;i++){
        gvr[i] += zcs[gm*768 + ci+i];
        gvz[i] += zcs[gm*768 + 256 + ci+i];
        gvn[i] += zcs[gm*768 + 512 + ci+i];
      }
    }
    #pragma unroll
    for (int i=0;i<CPL;i++){
      float rg = fast_sigmoid((float)hiR[i]*isr[i] + gvr[i]);
      float zg = fast_sigmoid((float)hiZ[i]*isz[i] + gvz[i]);
      float nn = fast_tanh(gvn[i] + rg*((float)hiN[i]*isn[i] + bnv[i]));
      hreg[i] = nn + zg*(hreg[i] - nn);
    }
    if constexpr (MODE == 0){
      // |h| <= 1 (tanh + convex combo from h0=0): clamp-free, v_perm pack
      int q0 = __float2int_rn(hreg[0]*127.f);
      int q1 = __float2int_rn(hreg[1]*127.f);
      int q2 = __float2int_rn(hreg[2]*127.f);
      int q3 = __float2int_rn(hreg[3]*127.f);
      u32 r01 = __builtin_amdgcn_perm((u32)q1, (u32)q0, 0x0C0C0400u);
      u32 r23 = __builtin_amdgcn_perm((u32)q3, (u32)q2, 0x04000C0Cu);
      *(u32*)&hbf[((cur^1)<<12) + gm*256 + (ci ^ (gm<<4))] = (r01 | r23);
    } else {
      int q0 = __float2int_rn(fminf(fmaxf(hreg[0]*HS, -127.f), 127.f));
      int q1 = __float2int_rn(fminf(fmaxf(hreg[1]*HS, -127.f), 127.f));
      *(u16*)&hbf[((cur^1)<<12) + gm*256 + (ci ^ (gm<<4))] =
          (u16)((q0 & 255) | ((q1 & 255) << 8));
      // ys: truncated bf16 pair via one v_perm (<=1ulp vs RNE)
      u32 fa = __builtin_bit_cast(u32, hreg[0]);
      u32 fb = __builtin_bit_cast(u32, hreg[1]);
      u32 v = __builtin_amdgcn_perm(fb, fa, 0x07060302u);
      *(u32*)&ys[((size_t)(b0+gm)*127 + t)*256 + ci] = v;
    }
    __syncthreads();
    cur ^= 1;
  }

  if (MODE == 0){
    #pragma unroll
    for (int i=0;i<CPL;i++)
      out_h[(size_t)(b0+gm)*512 + (fwd ? 0 : 256) + ci+i] = hreg[i];
  }
}

// ---------------- VQ: z, argmin codebook, Q, idx, decoder h0, zc ----------------
__global__ __launch_bounds__(64) void k_vq(
    const float* __restrict__ outH, const float* __restrict__ Wdown, const float* __restrict__ bdown,
    const float* __restrict__ cb, const float* __restrict__ Wup, const float* __restrict__ bup,
    const float* __restrict__ Wihd, const float* __restrict__ bihd, const float* __restrict__ bhhd,
    float* __restrict__ hidden, float* __restrict__ zc, float* __restrict__ dout){
  const int b = blockIdx.x;
  const int lane = threadIdx.x;
  __shared__ float oh[512];
  __shared__ float zsh[32];
  __shared__ float qsh[32];
  {
    const float* src = outH + (size_t)b*512 + lane*8;
    *(float4*)&oh[lane*8]   = *(const float4*)src;
    *(float4*)&oh[lane*8+4] = *(const float4*)(src+4);
  }
  __syncthreads();
  if (lane < 32){
    float acc = bdown[lane];
    const float* wr = Wdown + lane*512;
    for (int k=0;k<512;k++) acc += wr[k]*oh[k];
    zsh[lane] = acc;
  }
  __syncthreads();
  float bd = 3.4e38f; int bi = 0;
  for (int c8=0;c8<8;c8++){
    const int c = lane*8 + c8;
    const float* cr = cb + c*32;
    float d = 0.f;
    #pragma unroll
    for (int k=0;k<32;k++){ float df = zsh[k]-cr[k]; d += df*df; }
    if (d < bd){ bd = d; bi = c; }
  }
  #pragma unroll
  for (int offm=32; offm>0; offm>>=1){
    float od = __shfl_xor(bd, offm);
    int   oi = __shfl_xor(bi, offm);
    if (od < bd || (od == bd && oi < bi)){ bd = od; bi = oi; }
  }
  if (lane == 0){
    atomicAdd(&dout[Q_OFF], bd * (0.2f/32.f));
    dout[IDX_OFF + b] = (float)bi;
  }
  if (lane < 32) qsh[lane] = cb[(size_t)bi*32 + lane];
  __syncthreads();
  #pragma unroll
  for (int i=0;i<4;i++){
    const int o = lane*4 + i;
    float acc = bup[o];
    const float* wr = Wup + o*32;
    #pragma unroll
    for (int k=0;k<32;k++) acc += wr[k]*qsh[k];
    hidden[(size_t)b*256 + o] = acc;
  }
  #pragma unroll
  for (int i=0;i<12;i++){
    const int o = lane*12 + i;
    float acc = bihd[o] + (o < 512 ? bhhd[o] : 0.f);
    const float* wr = Wihd + (size_t)o*96;
    #pragma unroll
    for (int k=0;k<32;k++) acc += wr[k]*qsh[k];
    zc[(size_t)b*768 + o] = acc;
  }
}

// ---------------- output: logits, log-softmax, nll, argmax ----------------
__global__ __launch_bounds__(256) void k_out(
    const u16* __restrict__ ys, const u16* __restrict__ Wo,
    const float* __restrict__ bout, const int* __restrict__ x,
    float* __restrict__ dout){
  const int tid = threadIdx.x;
  const int w = tid >> 6, lane = tid & 63;
  const int l15 = lane & 15, lhi = lane >> 4;
  __shared__ float lg[4][32][66];
  const int rows0 = blockIdx.x*128 + w*32;
  const f32x4 fz = {0.f,0.f,0.f,0.f};
  #pragma unroll
  for (int mt=0; mt<2; mt++){
    const int rb = rows0 + mt*16;
    f32x4 acc[4];
    #pragma unroll
    for (int nt=0;nt<4;nt++) acc[nt] = fz;
    #pragma unroll
    for (int kt=0; kt<8; kt++){
      short8 a = *(const short8*)&ys[(size_t)(rb + l15)*256 + kt*32 + lhi*8];
      #pragma unroll
      for (int nt=0; nt<4; nt++){
        short8 bb = *(const short8*)&Wo[(size_t)(nt*16 + l15)*256 + kt*32 + lhi*8];
        acc[nt] = __builtin_amdgcn_mfma_f32_16x16x32_bf16(a, bb, acc[nt], 0, 0, 0);
      }
    }
    #pragma unroll
    for (int nt=0;nt<4;nt++){
      const int col = nt*16 + l15;
      const float bo = (col < 51) ? bout[col] : 0.f;
      #pragma unroll
      for (int r=0;r<4;r++){
        float v = (col < 51) ? (acc[nt][r] + bo) : -1e30f;
        lg[w][mt*16 + lhi*4 + r][col] = v;
      }
    }
  }
  __syncthreads();
  float xl = 0.f, ct = 0.f;
  if (lane < 32){
    const int grow = rows0 + lane;
    const float* Lr = &lg[w][lane][0];
    float m = Lr[0]; int am = 0;
    for (int i=1;i<51;i++){ float v = Lr[i]; if (v > m){ m = v; am = i; } }
    float s = 0.f;
    for (int i=0;i<51;i++) s += __expf(Lr[i] - m);
    const int bb = grow / 127;
    const int tt = grow - bb*127;
    const int tgt = x[bb*128 + tt + 1];
    const float nll = (m + __logf(s)) - Lr[tgt];
    const float mk = (tgt != 0) ? 1.f : 0.f;
    dout[PRED_OFF + grow] = (float)am;
    xl = nll * mk; ct = mk;
  }
  #pragma unroll
  for (int off=32; off>0; off>>=1){
    xl += __shfl_xor(xl, off);
    ct += __shfl_xor(ct, off);
  }
  if (lane == 0){
    atomicAdd(&dout[XLOSS_OFF], xl);
    atomicAdd(&dout[NPAD_OFF], ct);
  }
}

extern "C" void kernel_launch(void* const* d_in, const int* in_sizes, int n_in,
                              void* d_out, int out_size, void* d_ws, size_t ws_size,
                              hipStream_t stream){
  (void)in_sizes; (void)n_in; (void)out_size; (void)ws_size;
  const int*   x      = (const int*)  d_in[0];
  const float* emb_e  = (const float*)d_in[1];
  const float* emb_d  = (const float*)d_in[2];
  const float* Wih_f  = (const float*)d_in[3];
  const float* Whh_f  = (const float*)d_in[4];
  const float* bih_f  = (const float*)d_in[5];
  const float* bhh_f  = (const float*)d_in[6];
  const float* Wih_b  = (const float*)d_in[7];
  const float* Whh_b  = (const float*)d_in[8];
  const float* bih_b  = (const float*)d_in[9];
  const float* bhh_b  = (const float*)d_in[10];
  const float* Wdown  = (const float*)d_in[11];
  const float* bdown  = (const float*)d_in[12];
  const float* cbook  = (const float*)d_in[13];
  const float* Wup    = (const float*)d_in[14];
  const float* bup    = (const float*)d_in[15];
  const float* Wih_d  = (const float*)d_in[16];
  const float* Whh_d  = (const float*)d_in[17];
  const float* bih_d  = (const float*)d_in[18];
  const float* bhh_d  = (const float*)d_in[19];
  const float* Wout   = (const float*)d_in[20];
  const float* bout   = (const float*)d_in[21];
  float* dout = (float*)d_out;

  char* ws = (char*)d_ws;
  size_t off = 0;
  auto nxt = [&](size_t bytes)->char*{
    char* r = ws + off;
    off += (bytes + 255) & ~(size_t)255;
    return r;
  };
  signed char* Wq_f = (signed char*)nxt((size_t)196608);
  signed char* Wq_b = (signed char*)nxt((size_t)196608);
  signed char* Wq_d = (signed char*)nxt((size_t)196608);
  float* invF = (float*)nxt((size_t)768*4);
  float* invB = (float*)nxt((size_t)768*4);
  float* invD = (float*)nxt((size_t)768*4);
  float* Gf    = (float*)nxt((size_t)39168*4);
  float* Gb    = (float*)nxt((size_t)39168*4);
  float* Gd    = (float*)nxt((size_t)39168*4);
  u16*   Wo_bf = (u16*) nxt((size_t)16384*2);
  float* outH  = (float*)nxt((size_t)524288*4);
  float* hid   = (float*)nxt((size_t)262144*4);
  float* zcw   = (float*)nxt((size_t)786432*4);
  u16*   ysb   = (u16*)  nxt((size_t)33292288*2);

  hipLaunchKernelGGL(k_prep, dim3(1099), dim3(256), 0, stream,
                     Wout, Wo_bf,
                     Whh_f, Whh_b, Whh_d, Wq_f, Wq_b, Wq_d, invF, invB, invD,
                     emb_e, emb_d, Wih_f, bih_f, bhh_f, Wih_b, bih_b, bhh_b, Wih_d,
                     Gf, Gb, Gd, dout);
  hipLaunchKernelGGL((k_gru<0,8>), dim3(256), dim3(512), 0, stream,
                     Wq_f, Wq_b, invF, invB, Gf, Gb, bhh_f, bhh_b, x,
                     (const float*)nullptr, (const float*)nullptr, outH, (u16*)nullptr);
  hipLaunchKernelGGL(k_vq, dim3(1024), dim3(64), 0, stream,
                     outH, Wdown, bdown, cbook, Wup, bup, Wih_d, bih_d, bhh_d,
                     hid, zcw, dout);
  hipLaunchKernelGGL((k_gru<1,4>), dim3(256), dim3(512), 0, stream,
                     Wq_d, (const signed char*)nullptr, invD, (const float*)nullptr,
                     Gd, (const float*)nullptr, bhh_d, (const float*)nullptr, x,
                     zcw, hid, (float*)nullptr, ysb);
  hipLaunchKernelGGL(k_out, dim3(1016), dim3(256), 0, stream,
                     ysb, Wo_bf, bout, x, dout);
}